// Round 1
// baseline (359.301 us; speedup 1.0000x reference)
//
#include <hip/hip_runtime.h>

#define N_NODES 512
#define EDGES   8192
#define TREM    32
#define INJ_N   256

typedef __attribute__((ext_vector_type(4))) float        f32x4;
typedef __attribute__((ext_vector_type(4))) unsigned int u32x4;
typedef __attribute__((ext_vector_type(8))) __bf16       bf16x8;

// ---- dynamic LDS layout (bytes) ----
static constexpr int OFF_R0   = 0;          // 131072: 4 col-quarters [q][node][32 cols bf16], swizzled
static constexpr int OFF_CSR  = 131072;     // 16384 : u16[8192] csr src ids; later aliased: psum/pwsum
static constexpr int OFF_OFFS = 147456;     // 2064  : int[516] csr row offsets
static constexpr int OFF_CUR  = 149520;     // 2048  : int[512] counters/cursor; later: remains-weight
static constexpr int OFF_DINV = 151568;     // 2048  : float[512]
static constexpr int OFF_SUB  = 153616;     // 2048  : int[512] subset
static constexpr int OFF_REM  = 155664;     // 128   : int[32] remains
static constexpr int OFF_RU   = 155792;     // 512   : float[128] ru_inj
static constexpr int OFF_HID  = 156304;     // 1536  : float[384] hidden
static constexpr int OFF_MISC = 157840;     // 128   : mapping, wave totals, reduce temps
static constexpr int SMEM_SZ  = 157968;     // < 163840

__device__ __forceinline__ unsigned f2bfu(float f){
  unsigned u = __float_as_uint(f);
  return (u + 0x7fffu + ((u >> 16) & 1u)) >> 16;     // RNE f32->bf16
}
__device__ __forceinline__ float bflo(unsigned v){ return __uint_as_float(v << 16); }
__device__ __forceinline__ float bfhi(unsigned v){ return __uint_as_float(v & 0xffff0000u); }
__device__ __forceinline__ int qbyte(int node, int col){   // byte offset in R0
  int q = col >> 5, cq = col & 31;
  return (q << 15) + (node << 6) + ((cq << 1) ^ ((node & 3) << 4));
}
__device__ __forceinline__ float leaky(float x){ return x >= 0.f ? x : 0.01f * x; }

// GEMM: R0 quarters (512x128 bf16, swizzled) @ W(global f32 128x128) -> acc (per-wave 64x128)
__device__ __forceinline__ void gemm_128(char* smem, const float* __restrict__ W,
                                         f32x4 (&acc)[4][8], int wv, int lane){
  const int l15 = lane & 15, l4 = lane >> 4;
  #pragma unroll
  for (int kk = 0; kk < 4; ++kk){
    bf16x8 a[4];
    #pragma unroll
    for (int rb = 0; rb < 4; ++rb){
      int row  = (wv << 6) + (rb << 4) + l15;
      int byte = (kk << 15) + (row << 6) + ((l4 << 4) ^ ((row & 3) << 4));
      a[rb] = *(const bf16x8*)(smem + byte);
    }
    const float* wbase = W + (kk * 32 + (l4 << 3)) * 128 + l15;   // W[k][c] row-major
    #pragma unroll
    for (int cb = 0; cb < 8; ++cb){
      u32x4 bw;
      #pragma unroll
      for (int i = 0; i < 4; ++i){
        unsigned lo = f2bfu(wbase[cb * 16 + (2 * i    ) * 128]);
        unsigned hi = f2bfu(wbase[cb * 16 + (2 * i + 1) * 128]);
        bw[i] = lo | (hi << 16);
      }
      bf16x8 b = __builtin_bit_cast(bf16x8, bw);
      #pragma unroll
      for (int rb = 0; rb < 4; ++rb)
        acc[rb][cb] = __builtin_amdgcn_mfma_f32_16x16x32_bf16(a[rb], b, acc[rb][cb], 0, 0, 0);
    }
  }
}

// store per-wave acc (xw) as bf16 back into R0 quarters (swizzled)
__device__ __forceinline__ void store_acc_bf16(char* smem, const f32x4 (&acc)[4][8], int wv, int lane){
  const int l15 = lane & 15, l4 = lane >> 4;
  #pragma unroll
  for (int rb = 0; rb < 4; ++rb)
    #pragma unroll
    for (int cb = 0; cb < 8; ++cb)
      #pragma unroll
      for (int r = 0; r < 4; ++r){
        int row = (wv << 6) + (rb << 4) + (l4 << 2) + r;   // D: row=(lane>>4)*4+reg, col=lane&15
        int col = (cb << 4) + l15;
        *(unsigned short*)(smem + qbyte(row, col)) = (unsigned short)f2bfu(acc[rb][cb][r]);
      }
}

// GCN propagate for col-quarter q: h[:,q] = leaky( sum_in norm * xw[:,q] + b ), written in-place
__device__ __forceinline__ void prop_pass(char* smem, int q, int n, const float* __restrict__ bias,
                                          const float* dinv, const unsigned short* csr, const int* offs){
  float dn = dinv[n];
  float hq[32];
  {   // self loop: norm = dinv[n]^2
    float nw = dn * dn;
    #pragma unroll
    for (int u = 0; u < 4; ++u){
      u32x4 v = *(const u32x4*)(smem + (q << 15) + (n << 6) + ((u << 4) ^ ((n & 3) << 4)));
      #pragma unroll
      for (int i = 0; i < 4; ++i){
        hq[u * 8 + 2 * i    ] = nw * bflo(v[i]);
        hq[u * 8 + 2 * i + 1] = nw * bfhi(v[i]);
      }
    }
  }
  int e1 = offs[n + 1];
  for (int e = offs[n]; e < e1; ++e){
    int s = csr[e];
    float nw = dn * dinv[s];
    #pragma unroll
    for (int u = 0; u < 4; ++u){
      u32x4 v = *(const u32x4*)(smem + (q << 15) + (s << 6) + ((u << 4) ^ ((s & 3) << 4)));
      #pragma unroll
      for (int i = 0; i < 4; ++i){
        hq[u * 8 + 2 * i    ] += nw * bflo(v[i]);
        hq[u * 8 + 2 * i + 1] += nw * bfhi(v[i]);
      }
    }
  }
  #pragma unroll
  for (int j = 0; j < 32; ++j) hq[j] = leaky(hq[j] + bias[q * 32 + j]);
  __syncthreads();          // all reads of quarter q done
  #pragma unroll
  for (int u = 0; u < 4; ++u){
    u32x4 v;
    #pragma unroll
    for (int i = 0; i < 4; ++i)
      v[i] = f2bfu(hq[u * 8 + 2 * i]) | (f2bfu(hq[u * 8 + 2 * i + 1]) << 16);
    *(u32x4*)(smem + (q << 15) + (n << 6) + ((u << 4) ^ ((n & 3) << 4))) = v;
  }
  __syncthreads();
}

__global__ __launch_bounds__(512, 2) void fg_main(
    const float* __restrict__ feats, const int* __restrict__ ei_g,
    const int* __restrict__ subset_g, const int* __restrict__ rem_g,
    const int* __restrict__ map_g,
    const float* __restrict__ W1, const float* __restrict__ b1,
    const float* __restrict__ W2, const float* __restrict__ b2,
    const float* __restrict__ Wg, const float* __restrict__ bg,
    const float* __restrict__ eps_g,
    float* __restrict__ out, float* __restrict__ ws)
{
  extern __shared__ __align__(16) char smem[];
  const int inj = blockIdx.x;
  const int tid = threadIdx.x;
  const int lane = tid & 63, wv = tid >> 6;

  unsigned short* csr = (unsigned short*)(smem + OFF_CSR);
  int*   offs = (int*)  (smem + OFF_OFFS);
  int*   cur  = (int*)  (smem + OFF_CUR);
  float* dinv = (float*)(smem + OFF_DINV);
  int*   sub  = (int*)  (smem + OFF_SUB);
  int*   rem  = (int*)  (smem + OFF_REM);
  float* ru   = (float*)(smem + OFF_RU);
  float* hid  = (float*)(smem + OFF_HID);
  int*   misc = (int*)  (smem + OFF_MISC);
  float* redf = (float*)(smem + OFF_MISC + 48);

  // ---- phase 0: indices + zero counters ----
  sub[tid] = subset_g[inj * N_NODES + tid];
  if (tid < TREM) rem[tid] = rem_g[inj * TREM + tid];
  if (tid == 0) misc[0] = map_g[inj];
  cur[tid] = 0;
  __syncthreads();

  // ---- count in-degree ----
  const int* ei = ei_g + inj * 2 * EDGES;
  #pragma unroll
  for (int k = 0; k < 16; ++k){
    int d = ei[EDGES + (k << 9) + tid];
    atomicAdd(&cur[d], 1);
  }
  __syncthreads();

  // ---- dinv + exclusive scan (csr offsets) ----
  int myc = cur[tid];
  dinv[tid] = 1.0f / sqrtf((float)(myc + 1));          // deg includes self loop
  int v = myc;
  #pragma unroll
  for (int o = 1; o < 64; o <<= 1){
    int t2 = __shfl_up(v, o);
    if (lane >= o) v += t2;
  }
  if (lane == 63) misc[1 + wv] = v;
  __syncthreads();
  int base = 0;
  for (int i = 0; i < wv; ++i) base += misc[1 + i];
  int excl = base + v - myc;
  offs[tid] = excl;
  cur[tid]  = excl;                                    // cursor for fill
  if (tid == 0) offs[N_NODES] = EDGES;
  __syncthreads();

  // ---- fill CSR (by dst, store src u16) ----
  #pragma unroll
  for (int k = 0; k < 16; ++k){
    int e = (k << 9) + tid;
    int s = ei[e], d = ei[EDGES + e];
    int pos = atomicAdd(&cur[d], 1);
    csr[pos] = (unsigned short)s;
  }
  // ru_inj = mean of raw features over remains (f32)
  if (tid < 128){
    float s = 0.f;
    for (int j = 0; j < TREM; ++j)
      s += feats[(long)sub[rem[j]] * 128 + tid];
    ru[tid] = s * (1.f / 32.f);
  }
  __syncthreads();

  // ---- stage fs into R0 quarters (bf16, swizzled) ----
  {
    const float* frow = feats + (long)sub[tid] * 128;
    #pragma unroll
    for (int q = 0; q < 4; ++q)
      #pragma unroll
      for (int u = 0; u < 4; ++u){
        const float* p = frow + q * 32 + u * 8;
        u32x4 pk;
        #pragma unroll
        for (int i = 0; i < 4; ++i)
          pk[i] = f2bfu(p[2 * i]) | (f2bfu(p[2 * i + 1]) << 16);
        *(u32x4*)(smem + (q << 15) + (tid << 6) + ((u << 4) ^ ((tid & 3) << 4))) = pk;
      }
  }
  __syncthreads();

  // ---- layer 1 ----
  f32x4 acc[4][8];
  #pragma unroll
  for (int i = 0; i < 4; ++i)
    #pragma unroll
    for (int j = 0; j < 8; ++j) acc[i][j] = (f32x4){0.f, 0.f, 0.f, 0.f};
  gemm_128(smem, W1, acc, wv, lane);
  __syncthreads();
  store_acc_bf16(smem, acc, wv, lane);
  __syncthreads();
  for (int q = 0; q < 4; ++q) prop_pass(smem, q, tid, b1, dinv, csr, offs);

  // ---- layer 2 ----
  #pragma unroll
  for (int i = 0; i < 4; ++i)
    #pragma unroll
    for (int j = 0; j < 8; ++j) acc[i][j] = (f32x4){0.f, 0.f, 0.f, 0.f};
  gemm_128(smem, W2, acc, wv, lane);
  __syncthreads();
  store_acc_bf16(smem, acc, wv, lane);
  __syncthreads();
  for (int q = 0; q < 4; ++q) prop_pass(smem, q, tid, b2, dinv, csr, offs);

  // ---- remains multiplicity (reuse cur) ----
  cur[tid] = 0;
  __syncthreads();
  if (tid < TREM) atomicAdd(&cur[rem[tid]], 1);
  __syncthreads();

  // ---- column reductions over h2 (in R0): mean, inj row, remains-mean ----
  float* psum  = (float*)(smem + OFF_CSR);          // [8][128] (csr dead)
  float* pwsum = (float*)(smem + OFF_CSR + 4096);   // [8][128]
  {
    int cp = tid & 63;          // column pair
    int ch = tid >> 6;          // node chunk
    int c0 = cp * 2;
    int map = misc[0];
    float s0 = 0, s1 = 0, w0 = 0, w1 = 0;
    for (int k = 0; k < 64; ++k){
      int n = (ch << 6) + k;
      unsigned vv = *(const unsigned*)(smem + qbyte(n, c0));
      float lo = bflo(vv), hi = bfhi(vv);
      float wt = (float)cur[n];
      s0 += lo; s1 += hi;
      w0 += wt * lo; w1 += wt * hi;
      if (n == map){ hid[128 + c0] = lo; hid[128 + c0 + 1] = hi; }
    }
    psum [ch * 128 + c0] = s0;  psum [ch * 128 + c0 + 1] = s1;
    pwsum[ch * 128 + c0] = w0;  pwsum[ch * 128 + c0 + 1] = w1;
  }
  __syncthreads();
  if (tid < 128){
    float s = 0.f, t = 0.f;
    #pragma unroll
    for (int ch = 0; ch < 8; ++ch){ s += psum[ch * 128 + tid]; t += pwsum[ch * 128 + tid]; }
    hid[tid]       = s * (1.f / 512.f);
    hid[256 + tid] = t * (1.f / 32.f);
  }
  __syncthreads();

  // ---- fd = leaky(hidden @ Wg + bg); outputs + homophily partials ----
  if (tid < 128){
    float f0 = bg[tid], f1 = bg[128 + tid];
    #pragma unroll 8
    for (int j = 0; j < 384; ++j){
      float hj = hid[j];
      f0 += hj * Wg[j * 256 + tid];
      f1 += hj * Wg[j * 256 + 128 + tid];
    }
    f0 = leaky(f0); f1 = leaky(f1);
    float mu = f0;
    float sg = fabsf(f1) + 1e-9f;
    float ep = eps_g[inj * 128 + tid];
    float ft = fminf(fmaxf(mu + sg * ep, -1.f), 1.f);
    out[         inj * 128 + tid] = ft;
    out[32768 +  inj * 128 + tid] = mu;
    out[65536 +  inj * 128 + tid] = sg;
    float r = ru[tid];
    float pn = r * ft, pr = r * r, pf = ft * ft;
    #pragma unroll
    for (int o = 32; o > 0; o >>= 1){
      pn += __shfl_down(pn, o);
      pr += __shfl_down(pr, o);
      pf += __shfl_down(pf, o);
    }
    if (lane == 0){ redf[wv * 3 + 0] = pn; redf[wv * 3 + 1] = pr; redf[wv * 3 + 2] = pf; }
  }
  __syncthreads();
  if (tid == 0){
    float num = redf[0] + redf[3];
    float r2  = redf[1] + redf[4];
    float f2  = redf[2] + redf[5];
    float den = fmaxf(sqrtf(r2), 1e-8f) * fmaxf(sqrtf(f2), 1e-8f);
    ws[inj] = num / den;
  }
}

__global__ void fg_reduce(const float* __restrict__ ws, float* __restrict__ out){
  int t = threadIdx.x;
  float v = ws[t];
  #pragma unroll
  for (int o = 32; o > 0; o >>= 1) v += __shfl_down(v, o);
  __shared__ float tmp[4];
  if ((t & 63) == 0) tmp[t >> 6] = v;
  __syncthreads();
  if (t == 0) out[98304] = (tmp[0] + tmp[1] + tmp[2] + tmp[3]) * (1.f / 256.f);
}

extern "C" void kernel_launch(void* const* d_in, const int* in_sizes, int n_in,
                              void* d_out, int out_size, void* d_ws, size_t ws_size,
                              hipStream_t stream){
  (void)in_sizes; (void)n_in; (void)out_size; (void)ws_size;
  const float* feats = (const float*)d_in[0];
  const int*   ei    = (const int*)  d_in[1];
  const int*   sub   = (const int*)  d_in[2];
  const int*   rem   = (const int*)  d_in[3];
  const int*   map   = (const int*)  d_in[4];
  const float* W1    = (const float*)d_in[6];
  const float* b1    = (const float*)d_in[7];
  const float* W2    = (const float*)d_in[8];
  const float* b2    = (const float*)d_in[9];
  const float* Wg    = (const float*)d_in[10];
  const float* bg    = (const float*)d_in[11];
  const float* eps   = (const float*)d_in[12];
  float* out = (float*)d_out;
  float* ws  = (float*)d_ws;

  hipFuncSetAttribute(reinterpret_cast<const void*>(fg_main),
                      hipFuncAttributeMaxDynamicSharedMemorySize, SMEM_SZ);
  fg_main<<<INJ_N, 512, SMEM_SZ, stream>>>(feats, ei, sub, rem, map,
                                           W1, b1, W2, b2, Wg, bg, eps, out, ws);
  fg_reduce<<<1, 256, 0, stream>>>(ws, out);
}

// Round 4
// 306.603 us; speedup vs baseline: 1.1719x; 1.1719x over previous
//
#include <hip/hip_runtime.h>

#define N_NODES 512
#define EDGES   8192
#define TREM    32
#define INJ_N   256

typedef __attribute__((ext_vector_type(2))) float        f32x2;
typedef __attribute__((ext_vector_type(4))) float        f32x4;
typedef __attribute__((ext_vector_type(4))) unsigned int u32x4;
typedef __attribute__((ext_vector_type(8))) __bf16       bf16x8;

// ---- LDS layout (bytes) ----
static constexpr int OFF_R0   = 0;          // 131072: [node][128 cols bf16], 16B-unit swizzled (unit ^= node&7)
static constexpr int OFF_CSR  = 131072;     // 16384 : u16[8192] csr src ids; aliased later: psum/pwsum/wgp
static constexpr int OFF_OFFS = 147456;     // 2064  : int[513] csr row offsets
static constexpr int OFF_CUR  = 149520;     // 2048  : int[512] counters/cursor; later remains-mult
static constexpr int OFF_DINV = 151568;     // 2048  : float[512]
static constexpr int OFF_SUB  = 153616;     // 2048  : int[512]
static constexpr int OFF_PERM = 155664;     // 2048  : int[512] degree-sorted node order
static constexpr int OFF_REM  = 157712;     // 128   : int[32]
static constexpr int OFF_RU   = 157840;     // 512   : float[128]
static constexpr int OFF_HID  = 158352;     // 1536  : float[384]
static constexpr int OFF_HIST = 159888;     // 512   : int[64] hist + int[64] histcur
static constexpr int OFF_MISC = 160400;     // 128   : map, wave totals, redf
static constexpr int OFF_BIAS = 160528;     // 512   : float[128] staged bias
static constexpr int SMEM_SZ  = 161040;     // <= 163840

__device__ __forceinline__ unsigned f2bfu(float f){
  unsigned u = __float_as_uint(f);
  return (u + 0x7fffu + ((u >> 16) & 1u)) >> 16;     // RNE f32->bf16 (validated r1)
}
__device__ __forceinline__ float bflo(unsigned v){ return __uint_as_float(v << 16); }
__device__ __forceinline__ float bfhi(unsigned v){ return __uint_as_float(v & 0xffff0000u); }
__device__ __forceinline__ float leaky(float x){ return x >= 0.f ? x : 0.01f * x; }
// byte address of 16B unit u (cols u*8..u*8+7) of node n in R0
__device__ __forceinline__ int runit(int n, int u){ return (n << 8) | (((u ^ (n & 7))) << 4); }

// ---- prep: pack W (128x128 f32 row-major [k][c]) into B-operand MFMA fragments ----
// slot t = kk*512 + cb*64 + lane ; elem j = W[kk*32 + (lane>>4)*8 + j][cb*16 + (lane&15)]
__global__ void fg_prep(const float* __restrict__ W1, const float* __restrict__ W2,
                        unsigned* __restrict__ wt){
  int L = blockIdx.x;
  const float* W = L ? W2 : W1;
  unsigned* o = wt + L * 8192;
  for (int t = threadIdx.x; t < 2048; t += 256){
    int kk = t >> 9, cb = (t >> 6) & 7, lane = t & 63;
    int l15 = lane & 15, l4 = lane >> 4;
    int kb = kk * 32 + l4 * 8, c = cb * 16 + l15;
    #pragma unroll
    for (int i = 0; i < 4; ++i)
      o[t * 4 + i] = f2bfu(W[(kb + 2 * i) * 128 + c]) |
                     (f2bfu(W[(kb + 2 * i + 1) * 128 + c]) << 16);
  }
}

// round-1-orientation GEMM: A = node rows (LDS), B = W frags (wt), D[node][c]
__device__ __forceinline__ void gemm_rw(char* smem, const unsigned* __restrict__ wt,
                                        f32x4 (&acc)[4][8], int wv, int lane){
  const int l15 = lane & 15, l4 = lane >> 4;
  #pragma unroll
  for (int kk = 0; kk < 4; ++kk){
    bf16x8 a[4];
    #pragma unroll
    for (int rb = 0; rb < 4; ++rb){
      int row = (wv << 6) + (rb << 4) + l15;
      a[rb] = *(const bf16x8*)(smem + runit(row, (kk << 2) + l4));
    }
    #pragma unroll
    for (int cb = 0; cb < 8; ++cb){
      u32x4 bw = *(const u32x4*)(wt + (((kk << 3) + cb) << 8) + (lane << 2));
      bf16x8 b = __builtin_bit_cast(bf16x8, bw);
      #pragma unroll
      for (int rb = 0; rb < 4; ++rb)
        acc[rb][cb] = __builtin_amdgcn_mfma_f32_16x16x32_bf16(a[rb], b, acc[rb][cb], 0, 0, 0);
    }
  }
}

// round-1-style store: D[node][c], per-element u16 (row-layout swizzled address)
__device__ __forceinline__ void store_rw(char* smem, const f32x4 (&acc)[4][8], int wv, int lane){
  const int l15 = lane & 15, l4 = lane >> 4;
  #pragma unroll
  for (int rb = 0; rb < 4; ++rb)
    #pragma unroll
    for (int cb = 0; cb < 8; ++cb)
      #pragma unroll
      for (int r = 0; r < 4; ++r){
        int row = (wv << 6) + (rb << 4) + (l4 << 2) + r;   // D: row=(lane>>4)*4+reg
        int col = (cb << 4) + l15;                          // D: col=lane&15
        *(unsigned short*)(smem + ((row << 8) | (((col >> 3) ^ (row & 7)) << 4) |
                                   ((col & 7) << 1))) = (unsigned short)f2bfu(acc[rb][cb][r]);
      }
}

// full-width GCN propagate: node n (perm'd), all 128 cols, in-place after barrier
__device__ __forceinline__ void prop_pass(char* smem, int n, const float* bias_s,
                                          const float* dinv, const unsigned short* csr,
                                          const int* offs){
  float dn = dinv[n];
  f32x2 hq[64];
  {
    float w = dn * dn;
    #pragma unroll
    for (int u = 0; u < 16; ++u){
      u32x4 v = *(const u32x4*)(smem + runit(n, u));
      #pragma unroll
      for (int i = 0; i < 4; ++i)
        hq[u * 4 + i] = (f32x2){w * bflo(v[i]), w * bfhi(v[i])};
    }
  }
  int e1 = offs[n + 1];
  for (int e = offs[n]; e < e1; ++e){
    int s = csr[e];
    float w = dn * dinv[s];
    #pragma unroll
    for (int u = 0; u < 16; ++u){
      u32x4 v = *(const u32x4*)(smem + runit(s, u));
      #pragma unroll
      for (int i = 0; i < 4; ++i){
        hq[u * 4 + i].x += w * bflo(v[i]);
        hq[u * 4 + i].y += w * bfhi(v[i]);
      }
    }
  }
  #pragma unroll
  for (int j = 0; j < 64; ++j){
    hq[j].x = leaky(hq[j].x + bias_s[2 * j]);
    hq[j].y = leaky(hq[j].y + bias_s[2 * j + 1]);
  }
  __syncthreads();                       // all reads done before overwrite
  #pragma unroll
  for (int u = 0; u < 16; ++u){
    u32x4 o;
    #pragma unroll
    for (int i = 0; i < 4; ++i)
      o[i] = f2bfu(hq[u * 4 + i].x) | (f2bfu(hq[u * 4 + i].y) << 16);
    *(u32x4*)(smem + runit(n, u)) = o;
  }
  __syncthreads();
}

__global__ __launch_bounds__(512, 2) void fg_main(
    const float* __restrict__ feats, const int* __restrict__ ei_g,
    const int* __restrict__ subset_g, const int* __restrict__ rem_g,
    const int* __restrict__ map_g,
    const float* __restrict__ b1, const float* __restrict__ b2,
    const float* __restrict__ Wg, const float* __restrict__ bg,
    const float* __restrict__ eps_g,
    const unsigned* __restrict__ wt,
    float* __restrict__ out, float* __restrict__ ws_f)
{
  extern __shared__ __align__(16) char smem[];
  const int inj = blockIdx.x;
  const int tid = threadIdx.x;
  const int lane = tid & 63, wv = tid >> 6;

  unsigned short* csr  = (unsigned short*)(smem + OFF_CSR);
  int*   offs   = (int*)  (smem + OFF_OFFS);
  int*   cur    = (int*)  (smem + OFF_CUR);
  float* dinv   = (float*)(smem + OFF_DINV);
  int*   sub    = (int*)  (smem + OFF_SUB);
  int*   perm   = (int*)  (smem + OFF_PERM);
  int*   rem    = (int*)  (smem + OFF_REM);
  float* ru     = (float*)(smem + OFF_RU);
  float* hid    = (float*)(smem + OFF_HID);
  int*   hist   = (int*)  (smem + OFF_HIST);
  int*   histcur= (int*)  (smem + OFF_HIST + 256);
  int*   misc   = (int*)  (smem + OFF_MISC);
  float* redf   = (float*)(smem + OFF_MISC + 64);
  float* bias_s = (float*)(smem + OFF_BIAS);

  // ---- S0: indices, clear counters ----
  sub[tid] = subset_g[inj * N_NODES + tid];
  if (tid < TREM) rem[tid] = rem_g[inj * TREM + tid];
  if (tid == 0) misc[0] = map_g[inj];
  cur[tid] = 0;
  if (tid < 64) hist[tid] = 0;
  __syncthreads();

  // ---- S1: in-degree count ----
  const int* ei = ei_g + inj * 2 * EDGES;
  #pragma unroll
  for (int k = 0; k < 16; ++k)
    atomicAdd(&cur[ei[EDGES + (k << 9) + tid]], 1);
  __syncthreads();

  // ---- S2: dinv, wave scan, degree histogram ----
  int myc = cur[tid];
  dinv[tid] = 1.0f / sqrtf((float)(myc + 1));
  int v = myc;
  #pragma unroll
  for (int o = 1; o < 64; o <<= 1){
    int t2 = __shfl_up(v, o);
    if (lane >= o) v += t2;
  }
  if (lane == 63) misc[1 + wv] = v;
  atomicAdd(&hist[myc < 63 ? myc : 63], 1);
  __syncthreads();

  // ---- S3: csr offsets + histogram exclusive scan ----
  int base = 0;
  for (int i = 0; i < wv; ++i) base += misc[1 + i];
  int excl = base + v - myc;
  offs[tid] = excl;
  cur[tid]  = excl;
  if (tid == 0) offs[N_NODES] = EDGES;
  if (tid < 64){
    int hv = hist[tid], sv = hv;
    #pragma unroll
    for (int o = 1; o < 64; o <<= 1){
      int t2 = __shfl_up(sv, o);
      if (tid >= o) sv += t2;
    }
    histcur[tid] = sv - hv;            // exclusive
  }
  __syncthreads();

  // ---- S4: fill CSR, perm scatter, ru gather, stage fs, bias1 ----
  #pragma unroll
  for (int k = 0; k < 16; ++k){
    int e = (k << 9) + tid;
    int s = ei[e], d = ei[EDGES + e];
    int pos = atomicAdd(&cur[d], 1);
    csr[pos] = (unsigned short)s;
  }
  {
    int rank = atomicAdd(&histcur[myc < 63 ? myc : 63], 1);
    perm[rank] = tid;
  }
  if (tid < 128){
    float s = 0.f;
    for (int j = 0; j < TREM; ++j)
      s += feats[(long)sub[rem[j]] * 128 + tid];
    ru[tid] = s * (1.f / 32.f);
  }
  if (tid >= 384) bias_s[tid & 127] = b1[tid & 127];
  {
    const float* frow = feats + (long)sub[tid] * 128;
    #pragma unroll
    for (int u = 0; u < 16; ++u){
      f32x4 a = *(const f32x4*)(frow + u * 8);
      f32x4 b = *(const f32x4*)(frow + u * 8 + 4);
      u32x4 pk;
      pk[0] = f2bfu(a.x) | (f2bfu(a.y) << 16);
      pk[1] = f2bfu(a.z) | (f2bfu(a.w) << 16);
      pk[2] = f2bfu(b.x) | (f2bfu(b.y) << 16);
      pk[3] = f2bfu(b.z) | (f2bfu(b.w) << 16);
      *(u32x4*)(smem + runit(tid, u)) = pk;
    }
  }
  __syncthreads();

  // ---- layer 1 ----
  f32x4 acc[4][8];
  #pragma unroll
  for (int i = 0; i < 4; ++i)
    #pragma unroll
    for (int j = 0; j < 8; ++j) acc[i][j] = (f32x4){0.f, 0.f, 0.f, 0.f};
  gemm_rw(smem, wt, acc, wv, lane);
  __syncthreads();
  store_rw(smem, acc, wv, lane);
  __syncthreads();
  prop_pass(smem, perm[tid], bias_s, dinv, csr, offs);

  // ---- layer 2 ----
  if (tid < 128) bias_s[tid] = b2[tid];
  #pragma unroll
  for (int i = 0; i < 4; ++i)
    #pragma unroll
    for (int j = 0; j < 8; ++j) acc[i][j] = (f32x4){0.f, 0.f, 0.f, 0.f};
  gemm_rw(smem, wt + 8192, acc, wv, lane);
  __syncthreads();
  store_rw(smem, acc, wv, lane);
  __syncthreads();
  prop_pass(smem, perm[tid], bias_s, dinv, csr, offs);

  // ---- S9: remains multiplicity ----
  cur[tid] = 0;
  __syncthreads();
  if (tid < TREM) atomicAdd(&cur[rem[tid]], 1);
  __syncthreads();

  // ---- S10: column reductions (mean / remains-mean / inj row) ----
  float* psum  = (float*)(smem + OFF_CSR);          // [8][128]
  float* pwsum = (float*)(smem + OFF_CSR + 4096);   // [8][128]
  {
    int cp = tid & 63, ch = tid >> 6;
    int c0 = cp * 2;
    int u = c0 >> 3, bo = (c0 & 7) << 1;
    float s0 = 0, s1 = 0, w0 = 0, w1 = 0;
    for (int k = 0; k < 64; ++k){
      int n = (ch << 6) + k;
      unsigned vv = *(const unsigned*)(smem + ((n << 8) | (((u ^ (n & 7))) << 4) | bo));
      float lo = bflo(vv), hi = bfhi(vv);
      float wtt = (float)cur[n];
      s0 += lo; s1 += hi;
      w0 += wtt * lo; w1 += wtt * hi;
    }
    psum [ch * 128 + c0] = s0;  psum [ch * 128 + c0 + 1] = s1;
    pwsum[ch * 128 + c0] = w0;  pwsum[ch * 128 + c0 + 1] = w1;
  }
  if (tid < 64){
    int mapn = misc[0];
    int c0 = tid * 2, u = c0 >> 3, bo = (c0 & 7) << 1;
    unsigned vv = *(const unsigned*)(smem + ((mapn << 8) | (((u ^ (mapn & 7))) << 4) | bo));
    hid[128 + c0] = bflo(vv); hid[128 + c0 + 1] = bfhi(vv);
  }
  __syncthreads();
  if (tid < 128){
    float s = 0.f, t = 0.f;
    #pragma unroll
    for (int ch = 0; ch < 8; ++ch){ s += psum[ch * 128 + tid]; t += pwsum[ch * 128 + tid]; }
    hid[tid]       = s * (1.f / 512.f);
    hid[256 + tid] = t * (1.f / 32.f);
  }
  __syncthreads();

  // ---- S11: fd = leaky(hidden @ Wg + bg), 4-way j-split ----
  float* wgp = (float*)(smem + OFF_CSR);            // [4][256]
  {
    int g = tid >> 7, c = tid & 127;
    float f0 = 0.f, f1 = 0.f;
    const float* wb = Wg + (g * 96) * 256;
    #pragma unroll 8
    for (int j = 0; j < 96; ++j){
      float hj = hid[g * 96 + j];
      f0 += hj * wb[j * 256 + c];
      f1 += hj * wb[j * 256 + 128 + c];
    }
    wgp[g * 256 + c]       = f0;
    wgp[g * 256 + 128 + c] = f1;
  }
  __syncthreads();
  if (tid < 128){
    float f0 = bg[tid], f1 = bg[128 + tid];
    #pragma unroll
    for (int g = 0; g < 4; ++g){
      f0 += wgp[g * 256 + tid];
      f1 += wgp[g * 256 + 128 + tid];
    }
    f0 = leaky(f0); f1 = leaky(f1);
    float mu = f0;
    float sg = fabsf(f1) + 1e-9f;
    float ep = eps_g[inj * 128 + tid];
    float ft = fminf(fmaxf(mu + sg * ep, -1.f), 1.f);
    out[         inj * 128 + tid] = ft;
    out[32768 +  inj * 128 + tid] = mu;
    out[65536 +  inj * 128 + tid] = sg;
    float r = ru[tid];
    float pn = r * ft, pr = r * r, pf = ft * ft;
    #pragma unroll
    for (int o = 32; o > 0; o >>= 1){
      pn += __shfl_down(pn, o);
      pr += __shfl_down(pr, o);
      pf += __shfl_down(pf, o);
    }
    if (lane == 0){ redf[wv * 3 + 0] = pn; redf[wv * 3 + 1] = pr; redf[wv * 3 + 2] = pf; }
  }
  __syncthreads();
  if (tid == 0){
    float num = redf[0] + redf[3];
    float r2  = redf[1] + redf[4];
    float f2  = redf[2] + redf[5];
    float den = fmaxf(sqrtf(r2), 1e-8f) * fmaxf(sqrtf(f2), 1e-8f);
    ws_f[inj] = num / den;
  }
}

__global__ void fg_reduce(const float* __restrict__ ws_f, float* __restrict__ out){
  int t = threadIdx.x;
  float v = ws_f[t];
  #pragma unroll
  for (int o = 32; o > 0; o >>= 1) v += __shfl_down(v, o);
  __shared__ float tmp[4];
  if ((t & 63) == 0) tmp[t >> 6] = v;
  __syncthreads();
  if (t == 0) out[98304] = (tmp[0] + tmp[1] + tmp[2] + tmp[3]) * (1.f / 256.f);
}

extern "C" void kernel_launch(void* const* d_in, const int* in_sizes, int n_in,
                              void* d_out, int out_size, void* d_ws, size_t ws_size,
                              hipStream_t stream){
  (void)in_sizes; (void)n_in; (void)out_size; (void)ws_size;
  const float* feats = (const float*)d_in[0];
  const int*   ei    = (const int*)  d_in[1];
  const int*   sub   = (const int*)  d_in[2];
  const int*   rem   = (const int*)  d_in[3];
  const int*   map   = (const int*)  d_in[4];
  const float* W1    = (const float*)d_in[6];
  const float* b1    = (const float*)d_in[7];
  const float* W2    = (const float*)d_in[8];
  const float* b2    = (const float*)d_in[9];
  const float* Wg    = (const float*)d_in[10];
  const float* bg    = (const float*)d_in[11];
  const float* eps   = (const float*)d_in[12];
  float* out = (float*)d_out;
  unsigned* wt = (unsigned*)d_ws;                       // 64 KB packed W frags
  float* ws_f  = (float*)((char*)d_ws + 65536);         // homophily partials

  fg_prep<<<2, 256, 0, stream>>>(W1, W2, wt);

  hipFuncSetAttribute(reinterpret_cast<const void*>(fg_main),
                      hipFuncAttributeMaxDynamicSharedMemorySize, SMEM_SZ);
  fg_main<<<INJ_N, 512, SMEM_SZ, stream>>>(feats, ei, sub, rem, map,
                                           b1, b2, Wg, bg, eps, wt, out, ws_f);
  fg_reduce<<<1, 256, 0, stream>>>(ws_f, out);
}

// Round 6
// 279.118 us; speedup vs baseline: 1.2873x; 1.0985x over previous
//
#include <hip/hip_runtime.h>

#define N_NODES 512
#define EDGES   8192
#define TREM    32
#define INJ_N   256

typedef __attribute__((ext_vector_type(2))) float        f32x2;
typedef __attribute__((ext_vector_type(4))) float        f32x4;
typedef __attribute__((ext_vector_type(4))) unsigned int u32x4;
typedef __attribute__((ext_vector_type(8))) __bf16       bf16x8;

// ---- LDS layout (bytes) ----
static constexpr int OFF_R0   = 0;          // 131072: [node][128 cols bf16], LINEAR rows (no swizzle)
static constexpr int OFF_CSR  = 131072;     // 16384 : u16[8192] csr src ids; aliased later: psum/pwsum/wgp
static constexpr int OFF_OFFS = 147456;     // 2064  : int[513] csr row offsets
static constexpr int OFF_CUR  = 149520;     // 2048  : int[512] counters/cursor; later remains-mult
static constexpr int OFF_DINV = 151568;     // 2048  : float[512]
static constexpr int OFF_SUB  = 153616;     // 2048  : int[512]
static constexpr int OFF_PERM = 155664;     // 2048  : int[512] degree-sorted node order
static constexpr int OFF_REM  = 157712;     // 128   : int[32]
static constexpr int OFF_RU   = 157840;     // 512   : float[128]
static constexpr int OFF_HID  = 158352;     // 1536  : float[384]
static constexpr int OFF_HIST = 159888;     // 512   : int[64] hist + int[64] histcur
static constexpr int OFF_MISC = 160400;     // 128   : map, wave totals, redf
static constexpr int OFF_BIAS = 160528;     // 512   : float[128] staged bias
static constexpr int SMEM_SZ  = 161040;     // <= 163840

__device__ __forceinline__ unsigned f2bfu(float f){
  unsigned u = __float_as_uint(f);
  return (u + 0x7fffu + ((u >> 16) & 1u)) >> 16;     // RNE f32->bf16 (validated r1)
}
__device__ __forceinline__ float bflo(unsigned v){ return __uint_as_float(v << 16); }
__device__ __forceinline__ float bfhi(unsigned v){ return __uint_as_float(v & 0xffff0000u); }
__device__ __forceinline__ float leaky(float x){ return x >= 0.f ? x : 0.01f * x; }
// byte address of 16B unit u (cols u*8..u*8+7) of node n in R0 — linear
__device__ __forceinline__ int runit(int n, int u){ return (n << 8) | (u << 4); }

// ---- prep: pack W (128x128 f32 row-major [k][c]) into B-operand MFMA fragments ----
// slot t = kk*512 + cb*64 + lane ; elem j = W[kk*32 + (lane>>4)*8 + j][cb*16 + (lane&15)]
__global__ void fg_prep(const float* __restrict__ W1, const float* __restrict__ W2,
                        unsigned* __restrict__ wt){
  int L = blockIdx.x;
  const float* W = L ? W2 : W1;
  unsigned* o = wt + L * 8192;
  for (int t = threadIdx.x; t < 2048; t += 256){
    int kk = t >> 9, cb = (t >> 6) & 7, lane = t & 63;
    int l15 = lane & 15, l4 = lane >> 4;
    int kb = kk * 32 + l4 * 8, c = cb * 16 + l15;
    #pragma unroll
    for (int i = 0; i < 4; ++i)
      o[t * 4 + i] = f2bfu(W[(kb + 2 * i) * 128 + c]) |
                     (f2bfu(W[(kb + 2 * i + 1) * 128 + c]) << 16);
  }
}

// GEMM (validated r1 orientation): A = node rows (LDS), B = W frags (wt), D[node][c]
__device__ __forceinline__ void gemm_rw(char* smem, const unsigned* __restrict__ wt,
                                        f32x4 (&acc)[4][8], int wv, int lane){
  const int l15 = lane & 15, l4 = lane >> 4;
  #pragma unroll
  for (int kk = 0; kk < 4; ++kk){
    bf16x8 a[4];
    #pragma unroll
    for (int rb = 0; rb < 4; ++rb){
      int row = (wv << 6) + (rb << 4) + l15;
      a[rb] = *(const bf16x8*)(smem + runit(row, (kk << 2) + l4));
    }
    #pragma unroll
    for (int cb = 0; cb < 8; ++cb){
      u32x4 bw = *(const u32x4*)(wt + (((kk << 3) + cb) << 8) + (lane << 2));
      bf16x8 b = __builtin_bit_cast(bf16x8, bw);
      #pragma unroll
      for (int rb = 0; rb < 4; ++rb)
        acc[rb][cb] = __builtin_amdgcn_mfma_f32_16x16x32_bf16(a[rb], b, acc[rb][cb], 0, 0, 0);
    }
  }
}

// store D[node][c] as bf16, per-element u16 (validated r1 D-layout)
__device__ __forceinline__ void store_rw(char* smem, const f32x4 (&acc)[4][8], int wv, int lane){
  const int l15 = lane & 15, l4 = lane >> 4;
  #pragma unroll
  for (int rb = 0; rb < 4; ++rb)
    #pragma unroll
    for (int cb = 0; cb < 8; ++cb)
      #pragma unroll
      for (int r = 0; r < 4; ++r){
        int row = (wv << 6) + (rb << 4) + (l4 << 2) + r;   // D: row=(lane>>4)*4+reg
        int col = (cb << 4) + l15;                          // D: col=lane&15
        *(unsigned short*)(smem + ((row << 8) | (col << 1))) = (unsigned short)f2bfu(acc[rb][cb][r]);
      }
}

// full-width GCN propagate, lane-rotated unit order (conflict-free banks)
__device__ __forceinline__ void prop_pass(char* smem, int n, const float* bias_s,
                                          const float* dinv, const unsigned short* csr,
                                          const int* offs, const int (&voff)[16]){
  float dn = dinv[n];
  f32x2 hq[64];
  {   // self term: dn * x_n  (whole sum scaled by dn at the end)
    int base = n << 8;
    #pragma unroll
    for (int t = 0; t < 16; ++t){
      u32x4 v = *(const u32x4*)(smem + base + voff[t]);
      #pragma unroll
      for (int i = 0; i < 4; ++i)
        hq[t * 4 + i] = (f32x2){dn * bflo(v[i]), dn * bfhi(v[i])};
    }
  }
  int e1 = offs[n + 1];
  for (int e = offs[n]; e < e1; ++e){
    int s = csr[e];
    float w = dinv[s];
    int base = s << 8;
    #pragma unroll
    for (int t = 0; t < 16; ++t){
      u32x4 v = *(const u32x4*)(smem + base + voff[t]);
      #pragma unroll
      for (int i = 0; i < 4; ++i){
        hq[t * 4 + i].x += w * bflo(v[i]);
        hq[t * 4 + i].y += w * bfhi(v[i]);
      }
    }
  }
  __syncthreads();                       // all reads done before overwrite
  int base = n << 8;
  #pragma unroll
  for (int t = 0; t < 16; ++t){
    const float* bp = bias_s + (voff[t] >> 1);   // float index p*8
    f32x4 ba = *(const f32x4*)bp;
    f32x4 bb = *(const f32x4*)(bp + 4);
    u32x4 o;
    o[0] = f2bfu(leaky(dn * hq[t*4+0].x + ba.x)) | (f2bfu(leaky(dn * hq[t*4+0].y + ba.y)) << 16);
    o[1] = f2bfu(leaky(dn * hq[t*4+1].x + ba.z)) | (f2bfu(leaky(dn * hq[t*4+1].y + ba.w)) << 16);
    o[2] = f2bfu(leaky(dn * hq[t*4+2].x + bb.x)) | (f2bfu(leaky(dn * hq[t*4+2].y + bb.y)) << 16);
    o[3] = f2bfu(leaky(dn * hq[t*4+3].x + bb.z)) | (f2bfu(leaky(dn * hq[t*4+3].y + bb.w)) << 16);
    *(u32x4*)(smem + base + voff[t]) = o;
  }
  __syncthreads();
}

__global__ __launch_bounds__(512, 2) void fg_main(
    const float* __restrict__ feats, const int* __restrict__ ei_g,
    const int* __restrict__ subset_g, const int* __restrict__ rem_g,
    const int* __restrict__ map_g,
    const float* __restrict__ b1, const float* __restrict__ b2,
    const float* __restrict__ Wg, const float* __restrict__ bg,
    const float* __restrict__ eps_g,
    const unsigned* __restrict__ wt,
    float* __restrict__ out, float* __restrict__ ws_f)
{
  extern __shared__ __align__(16) char smem[];
  const int inj = blockIdx.x;
  const int tid = threadIdx.x;
  const int lane = tid & 63, wv = tid >> 6;

  unsigned short* csr  = (unsigned short*)(smem + OFF_CSR);
  int*   offs   = (int*)  (smem + OFF_OFFS);
  int*   cur    = (int*)  (smem + OFF_CUR);
  float* dinv   = (float*)(smem + OFF_DINV);
  int*   sub    = (int*)  (smem + OFF_SUB);
  int*   perm   = (int*)  (smem + OFF_PERM);
  int*   rem    = (int*)  (smem + OFF_REM);
  float* ru     = (float*)(smem + OFF_RU);
  float* hid    = (float*)(smem + OFF_HID);
  int*   hist   = (int*)  (smem + OFF_HIST);
  int*   histcur= (int*)  (smem + OFF_HIST + 256);
  int*   misc   = (int*)  (smem + OFF_MISC);
  float* redf   = (float*)(smem + OFF_MISC + 64);
  float* bias_s = (float*)(smem + OFF_BIAS);

  // lane-rotated unit byte-offsets: p = (lane+t)&15, voff = p<<4  (static reg array)
  int voff[16];
  #pragma unroll
  for (int t = 0; t < 16; ++t) voff[t] = (((lane + t) & 15) << 4);

  // ---- S0: indices, clear counters ----
  sub[tid] = subset_g[inj * N_NODES + tid];
  if (tid < TREM) rem[tid] = rem_g[inj * TREM + tid];
  if (tid == 0) misc[0] = map_g[inj];
  cur[tid] = 0;
  if (tid < 64) hist[tid] = 0;
  __syncthreads();

  // ---- S1: load edges to regs (int4), count in-degree ----
  const int* ei = ei_g + inj * 2 * EDGES;
  int4 es[4], ed[4];
  #pragma unroll
  for (int k = 0; k < 4; ++k){
    es[k] = *(const int4*)(ei + (tid << 4) + (k << 2));
    ed[k] = *(const int4*)(ei + EDGES + (tid << 4) + (k << 2));
  }
  #pragma unroll
  for (int k = 0; k < 4; ++k){
    atomicAdd(&cur[ed[k].x], 1); atomicAdd(&cur[ed[k].y], 1);
    atomicAdd(&cur[ed[k].z], 1); atomicAdd(&cur[ed[k].w], 1);
  }
  __syncthreads();

  // ---- S2: dinv, wave scan, degree histogram ----
  int myc = cur[tid];
  dinv[tid] = 1.0f / sqrtf((float)(myc + 1));
  int v = myc;
  #pragma unroll
  for (int o = 1; o < 64; o <<= 1){
    int t2 = __shfl_up(v, o);
    if (lane >= o) v += t2;
  }
  if (lane == 63) misc[1 + wv] = v;
  atomicAdd(&hist[myc < 63 ? myc : 63], 1);
  __syncthreads();

  // ---- S3: csr offsets + histogram exclusive scan ----
  int base = 0;
  for (int i = 0; i < wv; ++i) base += misc[1 + i];
  int excl = base + v - myc;
  offs[tid] = excl;
  cur[tid]  = excl;
  if (tid == 0) offs[N_NODES] = EDGES;
  if (tid < 64){
    int hv = hist[tid], sv = hv;
    #pragma unroll
    for (int o = 1; o < 64; o <<= 1){
      int t2 = __shfl_up(sv, o);
      if (tid >= o) sv += t2;
    }
    histcur[tid] = sv - hv;            // exclusive
  }
  __syncthreads();

  // ---- S4: fill CSR (from regs), perm scatter, ru gather, stage fs, bias1 ----
  #pragma unroll
  for (int k = 0; k < 4; ++k){
    int pos;
    pos = atomicAdd(&cur[ed[k].x], 1); csr[pos] = (unsigned short)es[k].x;
    pos = atomicAdd(&cur[ed[k].y], 1); csr[pos] = (unsigned short)es[k].y;
    pos = atomicAdd(&cur[ed[k].z], 1); csr[pos] = (unsigned short)es[k].z;
    pos = atomicAdd(&cur[ed[k].w], 1); csr[pos] = (unsigned short)es[k].w;
  }
  {
    int rank = atomicAdd(&histcur[myc < 63 ? myc : 63], 1);
    perm[rank] = tid;
  }
  if (tid < 128){
    float s = 0.f;
    for (int j = 0; j < TREM; ++j)
      s += feats[(long)sub[rem[j]] * 128 + tid];
    ru[tid] = s * (1.f / 32.f);
  }
  if (tid >= 384) bias_s[tid & 127] = b1[tid & 127];
  {
    const float* frow = feats + (long)sub[tid] * 128;
    #pragma unroll
    for (int t = 0; t < 16; ++t){
      const float* p = frow + (voff[t] >> 1);    // float index p*8
      f32x4 a = *(const f32x4*)p;
      f32x4 b = *(const f32x4*)(p + 4);
      u32x4 pk;
      pk[0] = f2bfu(a.x) | (f2bfu(a.y) << 16);
      pk[1] = f2bfu(a.z) | (f2bfu(a.w) << 16);
      pk[2] = f2bfu(b.x) | (f2bfu(b.y) << 16);
      pk[3] = f2bfu(b.z) | (f2bfu(b.w) << 16);
      *(u32x4*)(smem + (tid << 8) + voff[t]) = pk;
    }
  }
  __syncthreads();

  // ---- layer 1 ----
  f32x4 acc[4][8];
  #pragma unroll
  for (int i = 0; i < 4; ++i)
    #pragma unroll
    for (int j = 0; j < 8; ++j) acc[i][j] = (f32x4){0.f, 0.f, 0.f, 0.f};
  gemm_rw(smem, wt, acc, wv, lane);
  __syncthreads();
  store_rw(smem, acc, wv, lane);
  __syncthreads();
  prop_pass(smem, perm[tid], bias_s, dinv, csr, offs, voff);

  // ---- layer 2 ----
  if (tid < 128) bias_s[tid] = b2[tid];
  #pragma unroll
  for (int i = 0; i < 4; ++i)
    #pragma unroll
    for (int j = 0; j < 8; ++j) acc[i][j] = (f32x4){0.f, 0.f, 0.f, 0.f};
  gemm_rw(smem, wt + 8192, acc, wv, lane);
  __syncthreads();
  store_rw(smem, acc, wv, lane);
  __syncthreads();
  prop_pass(smem, perm[tid], bias_s, dinv, csr, offs, voff);

  // ---- S9: remains multiplicity ----
  cur[tid] = 0;
  __syncthreads();
  if (tid < TREM) atomicAdd(&cur[rem[tid]], 1);
  __syncthreads();

  // ---- S10: column reductions (mean / remains-mean / inj row) ----
  float* psum  = (float*)(smem + OFF_CSR);          // [8][128]
  float* pwsum = (float*)(smem + OFF_CSR + 4096);   // [8][128]
  {
    int cp = tid & 63, ch = tid >> 6;
    int c0 = cp * 2;
    int u = c0 >> 3, bo = (c0 & 7) << 1;
    float s0 = 0, s1 = 0, w0 = 0, w1 = 0;
    for (int k = 0; k < 64; ++k){
      int n = (ch << 6) + k;
      unsigned vv = *(const unsigned*)(smem + ((n << 8) | (u << 4) | bo));
      float lo = bflo(vv), hi = bfhi(vv);
      float wtt = (float)cur[n];
      s0 += lo; s1 += hi;
      w0 += wtt * lo; w1 += wtt * hi;
    }
    psum [ch * 128 + c0] = s0;  psum [ch * 128 + c0 + 1] = s1;
    pwsum[ch * 128 + c0] = w0;  pwsum[ch * 128 + c0 + 1] = w1;
  }
  if (tid < 64){
    int mapn = misc[0];
    int c0 = tid * 2, u = c0 >> 3, bo = (c0 & 7) << 1;
    unsigned vv = *(const unsigned*)(smem + ((mapn << 8) | (u << 4) | bo));
    hid[128 + c0] = bflo(vv); hid[128 + c0 + 1] = bfhi(vv);
  }
  __syncthreads();
  if (tid < 128){
    float s = 0.f, t = 0.f;
    #pragma unroll
    for (int ch = 0; ch < 8; ++ch){ s += psum[ch * 128 + tid]; t += pwsum[ch * 128 + tid]; }
    hid[tid]       = s * (1.f / 512.f);
    hid[256 + tid] = t * (1.f / 32.f);
  }
  __syncthreads();

  // ---- S11: fd = leaky(hidden @ Wg + bg), 4-way j-split ----
  float* wgp = (float*)(smem + OFF_CSR);            // [4][256]
  {
    int g = tid >> 7, c = tid & 127;
    float f0 = 0.f, f1 = 0.f;
    const float* wb = Wg + (g * 96) * 256;
    #pragma unroll 8
    for (int j = 0; j < 96; ++j){
      float hj = hid[g * 96 + j];
      f0 += hj * wb[j * 256 + c];
      f1 += hj * wb[j * 256 + 128 + c];
    }
    wgp[g * 256 + c]       = f0;
    wgp[g * 256 + 128 + c] = f1;
  }
  __syncthreads();
  if (tid < 128){
    float f0 = bg[tid], f1 = bg[128 + tid];
    #pragma unroll
    for (int g = 0; g < 4; ++g){
      f0 += wgp[g * 256 + tid];
      f1 += wgp[g * 256 + 128 + tid];
    }
    f0 = leaky(f0); f1 = leaky(f1);
    float mu = f0;
    float sg = fabsf(f1) + 1e-9f;
    float ep = eps_g[inj * 128 + tid];
    float ft = fminf(fmaxf(mu + sg * ep, -1.f), 1.f);
    out[         inj * 128 + tid] = ft;
    out[32768 +  inj * 128 + tid] = mu;
    out[65536 +  inj * 128 + tid] = sg;
    float r = ru[tid];
    float pn = r * ft, pr = r * r, pf = ft * ft;
    #pragma unroll
    for (int o = 32; o > 0; o >>= 1){
      pn += __shfl_down(pn, o);
      pr += __shfl_down(pr, o);
      pf += __shfl_down(pf, o);
    }
    if (lane == 0){ redf[wv * 3 + 0] = pn; redf[wv * 3 + 1] = pr; redf[wv * 3 + 2] = pf; }
  }
  __syncthreads();
  if (tid == 0){
    float num = redf[0] + redf[3];
    float r2  = redf[1] + redf[4];
    float f2  = redf[2] + redf[5];
    float den = fmaxf(sqrtf(r2), 1e-8f) * fmaxf(sqrtf(f2), 1e-8f);
    ws_f[inj] = num / den;
  }
}

__global__ void fg_reduce(const float* __restrict__ ws_f, float* __restrict__ out){
  int t = threadIdx.x;
  float v = ws_f[t];
  #pragma unroll
  for (int o = 32; o > 0; o >>= 1) v += __shfl_down(v, o);
  __shared__ float tmp[4];
  if ((t & 63) == 0) tmp[t >> 6] = v;
  __syncthreads();
  if (t == 0) out[98304] = (tmp[0] + tmp[1] + tmp[2] + tmp[3]) * (1.f / 256.f);
}

extern "C" void kernel_launch(void* const* d_in, const int* in_sizes, int n_in,
                              void* d_out, int out_size, void* d_ws, size_t ws_size,
                              hipStream_t stream){
  (void)in_sizes; (void)n_in; (void)out_size; (void)ws_size;
  const float* feats = (const float*)d_in[0];
  const int*   ei    = (const int*)  d_in[1];
  const int*   sub   = (const int*)  d_in[2];
  const int*   rem   = (const int*)  d_in[3];
  const int*   map   = (const int*)  d_in[4];
  const float* W1    = (const float*)d_in[6];
  const float* b1    = (const float*)d_in[7];
  const float* W2    = (const float*)d_in[8];
  const float* b2    = (const float*)d_in[9];
  const float* Wg    = (const float*)d_in[10];
  const float* bg    = (const float*)d_in[11];
  const float* eps   = (const float*)d_in[12];
  float* out = (float*)d_out;
  unsigned* wt = (unsigned*)d_ws;                       // 64 KB packed W frags
  float* ws_f  = (float*)((char*)d_ws + 65536);         // homophily partials

  fg_prep<<<2, 256, 0, stream>>>(W1, W2, wt);

  hipFuncSetAttribute(reinterpret_cast<const void*>(fg_main),
                      hipFuncAttributeMaxDynamicSharedMemorySize, SMEM_SZ);
  fg_main<<<INJ_N, 512, SMEM_SZ, stream>>>(feats, ei, sub, rem, map,
                                           b1, b2, Wg, bg, eps, wt, out, ws_f);
  fg_reduce<<<1, 256, 0, stream>>>(ws_f, out);
}

// Round 9
// 266.249 us; speedup vs baseline: 1.3495x; 1.0483x over previous
//
#include <hip/hip_runtime.h>

#define N_NODES 512
#define EDGES   8192
#define TREM    32
#define INJ_N   256

typedef __attribute__((ext_vector_type(2))) float        f32x2;
typedef __attribute__((ext_vector_type(4))) float        f32x4;
typedef __attribute__((ext_vector_type(4))) unsigned int u32x4;
typedef __attribute__((ext_vector_type(8))) __bf16       bf16x8;

// ---- LDS layout (bytes) ----
static constexpr int OFF_R0   = 0;          // 131072: [node][128 cols bf16], LINEAR rows
static constexpr int OFF_CSR  = 131072;     // 16384 : u16[8192] csr; aliased later: psum/pwsum/wgp
static constexpr int OFF_OFFS = 147456;     // 2064  : int[513] csr row offsets
static constexpr int OFF_CUR  = 149520;     // 2048  : int[512] counters/cursor; later remains-mult
static constexpr int OFF_DINV = 151568;     // 2048  : float[512]
static constexpr int OFF_SUB  = 153616;     // 2048  : int[512]
static constexpr int OFF_PERM = 155664;     // 2048  : int[512] degree-sorted node order
static constexpr int OFF_REM  = 157712;     // 128   : int[32]
static constexpr int OFF_RU   = 157840;     // 512   : float[128]
static constexpr int OFF_HID  = 158352;     // 1536  : float[384]
static constexpr int OFF_HIST = 159888;     // 512   : int[64] hist + int[64] histcur
static constexpr int OFF_MISC = 160400;     // 128   : map, wave totals, redf
static constexpr int OFF_BIAS = 160528;     // 512   : float[128] staged bias
static constexpr int SMEM_SZ  = 161040;     // <= 163840

__device__ __forceinline__ unsigned f2bfu(float f){
  unsigned u = __float_as_uint(f);
  return (u + 0x7fffu + ((u >> 16) & 1u)) >> 16;     // RNE f32->bf16 (validated r1)
}
__device__ __forceinline__ float bflo(unsigned v){ return __uint_as_float(v << 16); }
__device__ __forceinline__ float bfhi(unsigned v){ return __uint_as_float(v & 0xffff0000u); }
__device__ __forceinline__ float leaky(float x){ return x >= 0.f ? x : 0.01f * x; }
__device__ __forceinline__ int runit(int n, int u){ return (n << 8) | (u << 4); }

// ---- prep: pack W into B-operand MFMA fragments (8 blocks for latency) ----
__global__ void fg_prep(const float* __restrict__ W1, const float* __restrict__ W2,
                        unsigned* __restrict__ wt){
  int L = blockIdx.x >> 2, q = blockIdx.x & 3;
  const float* W = L ? W2 : W1;
  unsigned* o = wt + L * 8192;
  for (int t = q * 512 + threadIdx.x; t < q * 512 + 512; t += 256){
    int kk = t >> 9, cb = (t >> 6) & 7, lane = t & 63;
    int l15 = lane & 15, l4 = lane >> 4;
    int kb = kk * 32 + l4 * 8, c = cb * 16 + l15;
    #pragma unroll
    for (int i = 0; i < 4; ++i)
      o[t * 4 + i] = f2bfu(W[(kb + 2 * i) * 128 + c]) |
                     (f2bfu(W[(kb + 2 * i + 1) * 128 + c]) << 16);
  }
}

// GEMM (validated orientation): A = node rows (LDS), B = W frags (wt), D[node][c]
// 16 waves: wave wv owns rows wv*32..wv*32+31
__device__ __forceinline__ void gemm_rw(char* smem, const unsigned* __restrict__ wt,
                                        f32x4 (&acc)[2][8], int wv, int lane){
  const int l15 = lane & 15, l4 = lane >> 4;
  #pragma unroll
  for (int kk = 0; kk < 4; ++kk){
    bf16x8 a[2];
    #pragma unroll
    for (int rb = 0; rb < 2; ++rb){
      int row = (wv << 5) + (rb << 4) + l15;
      a[rb] = *(const bf16x8*)(smem + runit(row, (kk << 2) + l4));
    }
    #pragma unroll
    for (int cb = 0; cb < 8; ++cb){
      u32x4 bw = *(const u32x4*)(wt + (((kk << 3) + cb) << 8) + (lane << 2));
      bf16x8 b = __builtin_bit_cast(bf16x8, bw);
      #pragma unroll
      for (int rb = 0; rb < 2; ++rb)
        acc[rb][cb] = __builtin_amdgcn_mfma_f32_16x16x32_bf16(a[rb], b, acc[rb][cb], 0, 0, 0);
    }
  }
}

__device__ __forceinline__ void store_rw(char* smem, const f32x4 (&acc)[2][8], int wv, int lane){
  const int l15 = lane & 15, l4 = lane >> 4;
  #pragma unroll
  for (int rb = 0; rb < 2; ++rb)
    #pragma unroll
    for (int cb = 0; cb < 8; ++cb)
      #pragma unroll
      for (int r = 0; r < 4; ++r){
        int row = (wv << 5) + (rb << 4) + (l4 << 2) + r;   // D: row=(lane>>4)*4+reg
        int col = (cb << 4) + l15;                          // D: col=lane&15
        *(unsigned short*)(smem + ((row << 8) | (col << 1))) = (unsigned short)f2bfu(acc[rb][cb][r]);
      }
}

// half-row GCN propagate: node n, 64 cols (8 units), lane-rotated, edge-pair prefetch
__device__ __forceinline__ void prop_pass(char* smem, int n, const float* bias_s,
                                          const float* dinv, const unsigned short* csr,
                                          const int* offs, const int (&voff)[8]){
  float dn = dinv[n];
  f32x2 hq[32];
  {   // self term: x_n (scaled by dn with the final dn multiply)
    int base = n << 8;
    #pragma unroll
    for (int t = 0; t < 8; ++t){
      u32x4 v = *(const u32x4*)(smem + base + voff[t]);
      #pragma unroll
      for (int i = 0; i < 4; ++i)
        hq[t * 4 + i] = (f32x2){dn * bflo(v[i]), dn * bfhi(v[i])};
    }
  }
  int e0 = offs[n], e1 = offs[n + 1];
  int s = (e0 < e1) ? csr[e0] : 0;
  float w = dinv[s];
  for (int e = e0; e < e1; ){
    int   base = s << 8;
    float wc   = w;
    ++e;
    if (e < e1){ s = csr[e]; w = dinv[s]; }       // prefetch next edge
    #pragma unroll
    for (int t = 0; t < 8; ++t){
      u32x4 v = *(const u32x4*)(smem + base + voff[t]);
      #pragma unroll
      for (int i = 0; i < 4; ++i){
        hq[t * 4 + i].x += wc * bflo(v[i]);
        hq[t * 4 + i].y += wc * bfhi(v[i]);
      }
    }
  }
  __syncthreads();                       // all reads done before overwrite
  int base = n << 8;
  #pragma unroll
  for (int t = 0; t < 8; ++t){
    const float* bp = bias_s + (voff[t] >> 1);
    f32x4 ba = *(const f32x4*)bp;
    f32x4 bb = *(const f32x4*)(bp + 4);
    u32x4 o;
    o[0] = f2bfu(leaky(dn * hq[t*4+0].x + ba.x)) | (f2bfu(leaky(dn * hq[t*4+0].y + ba.y)) << 16);
    o[1] = f2bfu(leaky(dn * hq[t*4+1].x + ba.z)) | (f2bfu(leaky(dn * hq[t*4+1].y + ba.w)) << 16);
    o[2] = f2bfu(leaky(dn * hq[t*4+2].x + bb.x)) | (f2bfu(leaky(dn * hq[t*4+2].y + bb.y)) << 16);
    o[3] = f2bfu(leaky(dn * hq[t*4+3].x + bb.z)) | (f2bfu(leaky(dn * hq[t*4+3].y + bb.w)) << 16);
    *(u32x4*)(smem + base + voff[t]) = o;
  }
  __syncthreads();
}

__global__ __launch_bounds__(1024, 4) void fg_main(
    const float* __restrict__ feats, const int* __restrict__ ei_g,
    const int* __restrict__ subset_g, const int* __restrict__ rem_g,
    const int* __restrict__ map_g,
    const float* __restrict__ b1, const float* __restrict__ b2,
    const float* __restrict__ Wg, const float* __restrict__ bg,
    const float* __restrict__ eps_g,
    const unsigned* __restrict__ wt,
    float* __restrict__ out, float* __restrict__ ws_f)
{
  extern __shared__ __align__(16) char smem[];
  const int inj = blockIdx.x;
  const int tid = threadIdx.x;
  const int lane = tid & 63, wv = tid >> 6;      // 16 waves

  unsigned short* csr  = (unsigned short*)(smem + OFF_CSR);
  int*   offs   = (int*)  (smem + OFF_OFFS);
  int*   cur    = (int*)  (smem + OFF_CUR);
  float* dinv   = (float*)(smem + OFF_DINV);
  int*   sub    = (int*)  (smem + OFF_SUB);
  int*   perm   = (int*)  (smem + OFF_PERM);
  int*   rem    = (int*)  (smem + OFF_REM);
  float* ru     = (float*)(smem + OFF_RU);
  float* hid    = (float*)(smem + OFF_HID);
  int*   hist   = (int*)  (smem + OFF_HIST);
  int*   histcur= (int*)  (smem + OFF_HIST + 256);
  int*   misc   = (int*)  (smem + OFF_MISC);
  float* redf   = (float*)(smem + OFF_MISC + 64);
  float* bias_s = (float*)(smem + OFF_BIAS);

  const int half = tid >> 9;                     // 0: cols 0-63, 1: cols 64-127
  // lane-rotated unit byte-offsets within this thread's col-half
  int voff[8];
  #pragma unroll
  for (int t = 0; t < 8; ++t) voff[t] = (((half << 3) | ((lane + t) & 7)) << 4);

  // ---- S0: indices, clear counters ----
  if (tid < N_NODES) sub[tid] = subset_g[inj * N_NODES + tid];
  if (tid < TREM) rem[tid] = rem_g[inj * TREM + tid];
  if (tid == 0) misc[0] = map_g[inj];
  if (tid < N_NODES) cur[tid] = 0;
  if (tid < 64) hist[tid] = 0;
  __syncthreads();

  // ---- S1: edges to regs (8/thread), count in-degree ----
  const int* ei = ei_g + inj * 2 * EDGES;
  int4 es[2], ed[2];
  #pragma unroll
  for (int k = 0; k < 2; ++k){
    es[k] = *(const int4*)(ei + (tid << 3) + (k << 2));
    ed[k] = *(const int4*)(ei + EDGES + (tid << 3) + (k << 2));
  }
  #pragma unroll
  for (int k = 0; k < 2; ++k){
    atomicAdd(&cur[ed[k].x], 1); atomicAdd(&cur[ed[k].y], 1);
    atomicAdd(&cur[ed[k].z], 1); atomicAdd(&cur[ed[k].w], 1);
  }
  __syncthreads();

  // ---- S2: dinv, wave scan, degree histogram (threads 0-511) ----
  int myc = 0, v = 0;
  if (tid < N_NODES){
    myc = cur[tid];
    dinv[tid] = 1.0f / sqrtf((float)(myc + 1));
    v = myc;
    #pragma unroll
    for (int o = 1; o < 64; o <<= 1){
      int t2 = __shfl_up(v, o);
      if (lane >= o) v += t2;
    }
    if (lane == 63) misc[1 + wv] = v;
    atomicAdd(&hist[myc < 63 ? myc : 63], 1);
  }
  __syncthreads();

  // ---- S3: csr offsets + histogram exclusive scan ----
  if (tid < N_NODES){
    int base = 0;
    for (int i = 0; i < wv; ++i) base += misc[1 + i];
    int excl = base + v - myc;
    offs[tid] = excl;
    cur[tid]  = excl;
    if (tid == 0) offs[N_NODES] = EDGES;
  }
  if (tid < 64){
    int hv = hist[tid], sv = hv;
    #pragma unroll
    for (int o = 1; o < 64; o <<= 1){
      int t2 = __shfl_up(sv, o);
      if (tid >= o) sv += t2;
    }
    histcur[tid] = sv - hv;            // exclusive
  }
  __syncthreads();

  // ---- S4: fill CSR (from regs), perm scatter, ru gather, stage fs, bias1 ----
  #pragma unroll
  for (int k = 0; k < 2; ++k){
    int pos;
    pos = atomicAdd(&cur[ed[k].x], 1); csr[pos] = (unsigned short)es[k].x;
    pos = atomicAdd(&cur[ed[k].y], 1); csr[pos] = (unsigned short)es[k].y;
    pos = atomicAdd(&cur[ed[k].z], 1); csr[pos] = (unsigned short)es[k].z;
    pos = atomicAdd(&cur[ed[k].w], 1); csr[pos] = (unsigned short)es[k].w;
  }
  if (tid < N_NODES){
    int rank = atomicAdd(&histcur[myc < 63 ? myc : 63], 1);
    perm[rank] = tid;
  }
  if (tid < 128){
    float s = 0.f;
    for (int j = 0; j < TREM; ++j)
      s += feats[(long)sub[rem[j]] * 128 + tid];
    ru[tid] = s * (1.f / 32.f);
  }
  if (tid >= 896) bias_s[tid & 127] = b1[tid & 127];
  {
    int node = tid & 511;
    const float* frow = feats + (long)sub[node] * 128;
    #pragma unroll
    for (int t = 0; t < 8; ++t){
      const float* p = frow + (voff[t] >> 1);    // float index unit*8
      f32x4 a = *(const f32x4*)p;
      f32x4 b = *(const f32x4*)(p + 4);
      u32x4 pk;
      pk[0] = f2bfu(a.x) | (f2bfu(a.y) << 16);
      pk[1] = f2bfu(a.z) | (f2bfu(a.w) << 16);
      pk[2] = f2bfu(b.x) | (f2bfu(b.y) << 16);
      pk[3] = f2bfu(b.z) | (f2bfu(b.w) << 16);
      *(u32x4*)(smem + (node << 8) + voff[t]) = pk;
    }
  }
  __syncthreads();

  // node for prop: half-split, within-wave degree-similar (perm sorted)
  const int pnode_i = ((wv & 7) << 6) | lane;

  // ---- layer 1 ----
  f32x4 acc[2][8];
  #pragma unroll
  for (int i = 0; i < 2; ++i)
    #pragma unroll
    for (int j = 0; j < 8; ++j) acc[i][j] = (f32x4){0.f, 0.f, 0.f, 0.f};
  gemm_rw(smem, wt, acc, wv, lane);
  __syncthreads();
  store_rw(smem, acc, wv, lane);
  __syncthreads();
  prop_pass(smem, perm[pnode_i], bias_s, dinv, csr, offs, voff);

  // ---- layer 2 ----
  if (tid < 128) bias_s[tid] = b2[tid];
  #pragma unroll
  for (int i = 0; i < 2; ++i)
    #pragma unroll
    for (int j = 0; j < 8; ++j) acc[i][j] = (f32x4){0.f, 0.f, 0.f, 0.f};
  gemm_rw(smem, wt + 8192, acc, wv, lane);
  __syncthreads();
  store_rw(smem, acc, wv, lane);
  __syncthreads();
  prop_pass(smem, perm[pnode_i], bias_s, dinv, csr, offs, voff);

  // ---- S9: remains multiplicity ----
  if (tid < N_NODES) cur[tid] = 0;
  __syncthreads();
  if (tid < TREM) atomicAdd(&cur[rem[tid]], 1);
  __syncthreads();

  // ---- S10: column reductions (mean / remains-mean / inj row), 16 chunks ----
  float* psum  = (float*)(smem + OFF_CSR);          // [16][128]
  float* pwsum = (float*)(smem + OFF_CSR + 8192);   // [16][128]
  {
    int cp = tid & 63, ch = tid >> 6;               // ch 0..15, 32-node chunks
    int c0 = cp * 2;
    int u = c0 >> 3, bo = (c0 & 7) << 1;
    float s0 = 0, s1 = 0, w0 = 0, w1 = 0;
    for (int k = 0; k < 32; ++k){
      int n = (ch << 5) + k;
      unsigned vv = *(const unsigned*)(smem + ((n << 8) | (u << 4) | bo));
      float lo = bflo(vv), hi = bfhi(vv);
      float wtt = (float)cur[n];
      s0 += lo; s1 += hi;
      w0 += wtt * lo; w1 += wtt * hi;
    }
    psum [ch * 128 + c0] = s0;  psum [ch * 128 + c0 + 1] = s1;
    pwsum[ch * 128 + c0] = w0;  pwsum[ch * 128 + c0 + 1] = w1;
  }
  if (tid < 64){
    int mapn = misc[0];
    int c0 = tid * 2, u = c0 >> 3, bo = (c0 & 7) << 1;
    unsigned vv = *(const unsigned*)(smem + ((mapn << 8) | (u << 4) | bo));
    hid[128 + c0] = bflo(vv); hid[128 + c0 + 1] = bfhi(vv);
  }
  __syncthreads();
  if (tid < 128){
    float s = 0.f, t = 0.f;
    #pragma unroll
    for (int ch = 0; ch < 16; ++ch){ s += psum[ch * 128 + tid]; t += pwsum[ch * 128 + tid]; }
    hid[tid]       = s * (1.f / 512.f);
    hid[256 + tid] = t * (1.f / 32.f);
  }
  __syncthreads();

  // ---- S11: fd = leaky(hidden @ Wg + bg), 8-way j-split ----
  float* wgp = (float*)(smem + OFF_CSR);            // [8][256]
  {
    int g = tid >> 7, c = tid & 127;                // g 0..7, 48 rows each
    float f0 = 0.f, f1 = 0.f;
    const float* wb = Wg + (g * 48) * 256;
    #pragma unroll 8
    for (int j = 0; j < 48; ++j){
      float hj = hid[g * 48 + j];
      f0 += hj * wb[j * 256 + c];
      f1 += hj * wb[j * 256 + 128 + c];
    }
    wgp[g * 256 + c]       = f0;
    wgp[g * 256 + 128 + c] = f1;
  }
  __syncthreads();
  if (tid < 128){
    float f0 = bg[tid], f1 = bg[128 + tid];
    #pragma unroll
    for (int g = 0; g < 8; ++g){
      f0 += wgp[g * 256 + tid];
      f1 += wgp[g * 256 + 128 + tid];
    }
    f0 = leaky(f0); f1 = leaky(f1);
    float mu = f0;
    float sg = fabsf(f1) + 1e-9f;
    float ep = eps_g[inj * 128 + tid];
    float ft = fminf(fmaxf(mu + sg * ep, -1.f), 1.f);
    out[         inj * 128 + tid] = ft;
    out[32768 +  inj * 128 + tid] = mu;
    out[65536 +  inj * 128 + tid] = sg;
    float r = ru[tid];
    float pn = r * ft, pr = r * r, pf = ft * ft;
    #pragma unroll
    for (int o = 32; o > 0; o >>= 1){
      pn += __shfl_down(pn, o);
      pr += __shfl_down(pr, o);
      pf += __shfl_down(pf, o);
    }
    if (lane == 0){ redf[wv * 3 + 0] = pn; redf[wv * 3 + 1] = pr; redf[wv * 3 + 2] = pf; }
  }
  __syncthreads();
  if (tid == 0){
    float num = redf[0] + redf[3];
    float r2  = redf[1] + redf[4];
    float f2  = redf[2] + redf[5];
    float den = fmaxf(sqrtf(r2), 1e-8f) * fmaxf(sqrtf(f2), 1e-8f);
    ws_f[inj] = num / den;
  }
}

__global__ void fg_reduce(const float* __restrict__ ws_f, float* __restrict__ out){
  int t = threadIdx.x;
  float v = ws_f[t];
  #pragma unroll
  for (int o = 32; o > 0; o >>= 1) v += __shfl_down(v, o);
  __shared__ float tmp[4];
  if ((t & 63) == 0) tmp[t >> 6] = v;
  __syncthreads();
  if (t == 0) out[98304] = (tmp[0] + tmp[1] + tmp[2] + tmp[3]) * (1.f / 256.f);
}

extern "C" void kernel_launch(void* const* d_in, const int* in_sizes, int n_in,
                              void* d_out, int out_size, void* d_ws, size_t ws_size,
                              hipStream_t stream){
  (void)in_sizes; (void)n_in; (void)out_size; (void)ws_size;
  const float* feats = (const float*)d_in[0];
  const int*   ei    = (const int*)  d_in[1];
  const int*   sub   = (const int*)  d_in[2];
  const int*   rem   = (const int*)  d_in[3];
  const int*   map   = (const int*)  d_in[4];
  const float* W1    = (const float*)d_in[6];
  const float* b1    = (const float*)d_in[7];
  const float* W2    = (const float*)d_in[8];
  const float* b2    = (const float*)d_in[9];
  const float* Wg    = (const float*)d_in[10];
  const float* bg    = (const float*)d_in[11];
  const float* eps   = (const float*)d_in[12];
  float* out = (float*)d_out;
  unsigned* wt = (unsigned*)d_ws;                       // 64 KB packed W frags
  float* ws_f  = (float*)((char*)d_ws + 65536);         // homophily partials

  fg_prep<<<8, 256, 0, stream>>>(W1, W2, wt);

  hipFuncSetAttribute(reinterpret_cast<const void*>(fg_main),
                      hipFuncAttributeMaxDynamicSharedMemorySize, SMEM_SZ);
  fg_main<<<INJ_N, 1024, SMEM_SZ, stream>>>(feats, ei, sub, rem, map,
                                            b1, b2, Wg, bg, eps, wt, out, ws_f);
  fg_reduce<<<1, 256, 0, stream>>>(ws_f, out);
}